// Round 12
// baseline (372.077 us; speedup 1.0000x reference)
//
#include <hip/hip_runtime.h>

#define NNODES 50000
#define NEDGES 800000
#define F_IN   128
#define HID    256
#define NOUT   40
#define NBLK_SCAN ((NNODES + 255) / 256)  // 196
#define NBLK_CAST 6250                     // 50000*128/4/256
#define NBLK_DEG  2048                     // partitioned: 256 chunks x 8 groups
#define NBLK_PREP 432                      // 128 (W1) + 256 (W2) + 48 (Wc)
#define EDGE_CHUNK 3125                    // 800000 / 256
#define NODES_PER_G 6250                   // 50000 / 8
#define NCHUNK_AGG 1563                    // ceil(50000 / 32)

typedef __attribute__((ext_vector_type(8))) _Float16 f16x8;
typedef __attribute__((ext_vector_type(4))) float f32x4;

__device__ __forceinline__ unsigned short f2h(float f) {
  return __builtin_bit_cast(unsigned short, (_Float16)f);
}
__device__ __forceinline__ float h2f(unsigned short u) {
  return (float)__builtin_bit_cast(_Float16, u);
}

// ------- fused: x->fp16 SLICED cast | XCD-local degree | weight transpose ---
// Sliced layout: [slice][node][32 feats], slice = feat >> 5. Slab = 3.2 MB.

__global__ __launch_bounds__(256) void k_pre(const float* __restrict__ X,
                                             unsigned short* __restrict__ Xh,
                                             const int* __restrict__ dst,
                                             int* __restrict__ count,
                                             const float* __restrict__ W1,
                                             const float* __restrict__ W2,
                                             const float* __restrict__ Wc,
                                             unsigned short* __restrict__ T1,
                                             unsigned short* __restrict__ T2,
                                             unsigned short* __restrict__ Tc) {
  int b = blockIdx.x, t = threadIdx.x;
  if (b < NBLK_CAST) {
    int i = b * 256 + t;                 // float4 unit; 32 per node row
    int node = i >> 5, c = i & 31;       // c: 4-feat chunk within row
    int slab = c >> 3, off = (c & 7) * 4;
    float4 v = *reinterpret_cast<const float4*>(X + (size_t)i * 4);
    ushort4 o;
    o.x = f2h(v.x); o.y = f2h(v.y); o.z = f2h(v.z); o.w = f2h(v.w);
    *reinterpret_cast<ushort4*>(Xh + (size_t)slab * (NNODES * 32) +
                                (size_t)node * 32 + off) = o;
  } else if (b < NBLK_CAST + NBLK_DEG) {
    int db = b - NBLK_CAST;
    int g = b & 7;                 // hardware XCD (round-robin heuristic)
    int chunk = db >> 3;           // 0..255
    int lo = g * NODES_PER_G, hi = lo + NODES_PER_G;
    int base = chunk * EDGE_CHUNK;
    for (int i = base + t; i < base + EDGE_CHUNK; i += 256) {
      int d = dst[i];
      if (d >= lo && d < hi) atomicAdd(&count[d], 1);
    }
  } else {
    int pb = b - NBLK_CAST - NBLK_DEG;  // 0..431
    if (pb < 128) {                     // W1 [128][256] -> T1 [256][128]
      int idx = pb * 256 + t;
      int n = idx >> 7, k = idx & 127;
      T1[idx] = f2h(W1[(size_t)k * HID + n]);
    } else if (pb < 384) {              // W2 [256][256] -> T2 [256][256]
      int idx = (pb - 128) * 256 + t;
      int n = idx >> 8, k = idx & 255;
      T2[idx] = f2h(W2[(size_t)k * HID + n]);
    } else {                            // Wc [256][40] -> Tc [48][256] zero-pad
      int idx = (pb - 384) * 256 + t;
      int n = idx >> 8, k = idx & 255;
      float v = (n < NOUT) ? Wc[(size_t)k * NOUT + n] : 0.f;
      Tc[idx] = f2h(v);
    }
  }
}

// ---------------- CSR scan ----------------

__global__ __launch_bounds__(256) void k_scan1(const int* __restrict__ count,
                                               int* __restrict__ rowstart,
                                               int* __restrict__ bsum,
                                               float* __restrict__ dinv) {
  __shared__ int tmp[256];
  int t = threadIdx.x;
  int i = blockIdx.x * 256 + t;
  int v = (i < NNODES) ? count[i] : 0;
  if (i < NNODES) dinv[i] = rsqrtf((float)(v + 1));  // +1 self-loop
  tmp[t] = v;
  __syncthreads();
  for (int off = 1; off < 256; off <<= 1) {
    int x = (t >= off) ? tmp[t - off] : 0;
    __syncthreads();
    tmp[t] += x;
    __syncthreads();
  }
  if (i < NNODES) rowstart[i] = tmp[t] - v;  // exclusive within block
  if (t == 255) bsum[blockIdx.x] = tmp[255];
}

__global__ __launch_bounds__(256) void k_scan2(const int* __restrict__ bsum,
                                               int* __restrict__ boff) {
  __shared__ int tmp[256];
  int t = threadIdx.x;
  int v = (t < NBLK_SCAN) ? bsum[t] : 0;
  tmp[t] = v;
  __syncthreads();
  for (int off = 1; off < 256; off <<= 1) {
    int x = (t >= off) ? tmp[t - off] : 0;
    __syncthreads();
    tmp[t] += x;
    __syncthreads();
  }
  if (t < NBLK_SCAN) boff[t] = tmp[t] - v;  // exclusive
}

// ---------------- XCD-local scatter ----------------

__global__ __launch_bounds__(256) void k_scatter(const int* __restrict__ src,
                                                 const int* __restrict__ dst,
                                                 const int* __restrict__ rowstart,
                                                 const int* __restrict__ boff,
                                                 int* __restrict__ cursor,
                                                 int* __restrict__ csr) {
  int g = blockIdx.x & 7;
  int chunk = blockIdx.x >> 3;
  int lo = g * NODES_PER_G, hi = lo + NODES_PER_G;
  int base = chunk * EDGE_CHUNK;
  for (int i = base + threadIdx.x; i < base + EDGE_CHUNK; i += 256) {
    int d = dst[i];
    if (d >= lo && d < hi) {
      int p = rowstart[d] + boff[d >> 8] + atomicAdd(&cursor[d], 1);
      csr[p] = src[i];
    }
  }
}

// ---------------- feature-sliced XCD-resident aggregation, group-per-node ---
// X,Y sliced [NSLICE][N][32] fp16; blocks with blockIdx&(NSLICE-1)==g touch
// only slab g (3.2 MB -> one XCD's L2). ONE 8-lane group per node, lane owns
// 4 feats. 8x unroll + masked 8-wide tail -> 64 independent 64B gathers in
// flight per wave per pass (latency fix for R11's 4-deep chains).

template <int NSLICE>
__global__ __launch_bounds__(256) void k_aggs(const unsigned short* __restrict__ X,
                                              const int* __restrict__ rowstart,
                                              const int* __restrict__ boff,
                                              const int* __restrict__ csr,
                                              const float* __restrict__ dinv,
                                              unsigned short* __restrict__ Y) {
  constexpr int SSH = (NSLICE == 8) ? 3 : 2;
  int slice = blockIdx.x & (NSLICE - 1);
  int chunk = blockIdx.x >> SSH;
  const unsigned short* Xs = X + (size_t)slice * (NNODES * 32);
  unsigned short* Ys = Y + (size_t)slice * (NNODES * 32);
  int wave = threadIdx.x >> 6, lane = threadIdx.x & 63;
  int grp = lane >> 3, l8 = lane & 7;
  int node = (chunk * 4 + wave) * 8 + grp;   // one node per 8-lane group
  bool alive = node < NNODES;
  float di = alive ? dinv[node] : 0.f;
  int e = 0, end = 0;
  if (alive) {
    e = rowstart[node] + boff[node >> 8];
    end = (node + 1 < NNODES) ? rowstart[node + 1] + boff[(node + 1) >> 8] : NEDGES;
  }
  float a0 = 0.f, a1 = 0.f, a2 = 0.f, a3 = 0.f;
  const unsigned short* Xl = Xs + l8 * 4;    // lane's 4-feat column base

  for (; e + 8 <= end; e += 8) {
    int s[8];
#pragma unroll
    for (int i = 0; i < 8; i++) s[i] = csr[e + i];
    uint2 v[8];
#pragma unroll
    for (int i = 0; i < 8; i++)
      v[i] = *reinterpret_cast<const uint2*>(Xl + (size_t)s[i] * 32);
    float w[8];
#pragma unroll
    for (int i = 0; i < 8; i++) w[i] = dinv[s[i]] * di;
#pragma unroll
    for (int i = 0; i < 8; i++) {
      a0 = fmaf(h2f((unsigned short)v[i].x), w[i], a0);
      a1 = fmaf(h2f((unsigned short)(v[i].x >> 16)), w[i], a1);
      a2 = fmaf(h2f((unsigned short)v[i].y), w[i], a2);
      a3 = fmaf(h2f((unsigned short)(v[i].y >> 16)), w[i], a3);
    }
  }
  int rem = end - e;
  if (rem > 0) {  // one masked 8-wide pass: clamped index, zero weight
    int s[8];
#pragma unroll
    for (int i = 0; i < 8; i++) s[i] = csr[e + (i < rem ? i : 0)];
    uint2 v[8];
#pragma unroll
    for (int i = 0; i < 8; i++)
      v[i] = *reinterpret_cast<const uint2*>(Xl + (size_t)s[i] * 32);
    float w[8];
#pragma unroll
    for (int i = 0; i < 8; i++) w[i] = (i < rem) ? dinv[s[i]] * di : 0.f;
#pragma unroll
    for (int i = 0; i < 8; i++) {
      a0 = fmaf(h2f((unsigned short)v[i].x), w[i], a0);
      a1 = fmaf(h2f((unsigned short)(v[i].x >> 16)), w[i], a1);
      a2 = fmaf(h2f((unsigned short)v[i].y), w[i], a2);
      a3 = fmaf(h2f((unsigned short)(v[i].y >> 16)), w[i], a3);
    }
  }
  if (alive) {  // self-loop + 8B store (64B/group contiguous)
    uint2 v = *reinterpret_cast<const uint2*>(Xl + (size_t)node * 32);
    float dd = di * di;
    a0 = fmaf(h2f((unsigned short)v.x), dd, a0);
    a1 = fmaf(h2f((unsigned short)(v.x >> 16)), dd, a1);
    a2 = fmaf(h2f((unsigned short)v.y), dd, a2);
    a3 = fmaf(h2f((unsigned short)(v.y >> 16)), dd, a3);
    unsigned long long o =
        (unsigned long long)((unsigned)f2h(a0) | ((unsigned)f2h(a1) << 16)) |
        ((unsigned long long)((unsigned)f2h(a2) | ((unsigned)f2h(a3) << 16)) << 32);
    __builtin_nontemporal_store(o, reinterpret_cast<unsigned long long*>(
        Ys + (size_t)node * 32 + l8 * 4));
  }
}

// ---------------- fp16 MFMA GEMM, double-buffered ----------------
// A: ALAYOUT 0 = row-major [M][K]; 1 = sliced [K/32][M][32] (BK=32=slab).
// B fp16 transposed [Npad][K]. OMODE: 0 = f32 row-major, 1 = fp16 SLICED out.

template <int RELU, int OMODE, int ALAYOUT>
__global__ __launch_bounds__(256) void k_mgemm(const unsigned short* __restrict__ Ag,
                                               const unsigned short* __restrict__ Btg,
                                               const float* __restrict__ bias,
                                               void* __restrict__ Cout,
                                               int M, int Nc, int K) {
  __shared__ unsigned short Ah[2][128 * 40];
  __shared__ unsigned short Bh[2][128 * 40];
  int tid = threadIdx.x;
  int lane = tid & 63, w = tid >> 6;
  int wr = w >> 1, wc = w & 1;
  int bm = blockIdx.x * 128, bn = blockIdx.y * 128;
  int l15 = lane & 15, kg = lane >> 4;
  int row0 = tid >> 2, kq0 = (tid & 3) * 8;
  int gm0 = bm + row0, gm1 = bm + row0 + 64;

  f32x4 zero = {0.f, 0.f, 0.f, 0.f};
  f32x4 acc[4][4];
#pragma unroll
  for (int i = 0; i < 4; i++)
#pragma unroll
    for (int j = 0; j < 4; j++) acc[i][j] = zero;

  uint4 ra0, ra1, rb0, rb1;
  const uint4 z4 = {0, 0, 0, 0};
#define LOADT(KT)                                                                     \
  {                                                                                   \
    const unsigned short* Ab = ALAYOUT                                                \
        ? Ag + (size_t)((KT) >> 5) * ((size_t)M * 32) + kq0                           \
        : Ag + (size_t)(KT) + kq0;                                                    \
    const size_t astr = ALAYOUT ? 32 : (size_t)K;                                     \
    ra0 = z4; ra1 = z4;                                                               \
    if (gm0 < M) ra0 = *reinterpret_cast<const uint4*>(Ab + (size_t)gm0 * astr);      \
    if (gm1 < M) ra1 = *reinterpret_cast<const uint4*>(Ab + (size_t)gm1 * astr);      \
    rb0 = *reinterpret_cast<const uint4*>(Btg + (size_t)(bn + row0) * K + (KT) + kq0);\
    rb1 = *reinterpret_cast<const uint4*>(Btg + (size_t)(bn + row0 + 64) * K + (KT) + kq0);\
  }
#define STORET(B)                                                       \
  {                                                                     \
    *reinterpret_cast<uint4*>(&Ah[B][row0 * 40 + kq0]) = ra0;           \
    *reinterpret_cast<uint4*>(&Ah[B][(row0 + 64) * 40 + kq0]) = ra1;    \
    *reinterpret_cast<uint4*>(&Bh[B][row0 * 40 + kq0]) = rb0;           \
    *reinterpret_cast<uint4*>(&Bh[B][(row0 + 64) * 40 + kq0]) = rb1;    \
  }

  LOADT(0);
  STORET(0);
  __syncthreads();
  int nt = K >> 5, cur = 0;
  for (int t = 0; t < nt; t++) {
    bool pf = (t + 1 < nt);
    if (pf) LOADT((t + 1) << 5);
    f16x8 fa[4], fb[4];
#pragma unroll
    for (int f = 0; f < 4; f++) {
      fa[f] = *reinterpret_cast<const f16x8*>(&Ah[cur][(wr * 64 + f * 16 + l15) * 40 + kg * 8]);
      fb[f] = *reinterpret_cast<const f16x8*>(&Bh[cur][(wc * 64 + f * 16 + l15) * 40 + kg * 8]);
    }
#pragma unroll
    for (int i = 0; i < 4; i++)
#pragma unroll
      for (int j = 0; j < 4; j++)
        acc[i][j] = __builtin_amdgcn_mfma_f32_16x16x32_f16(fa[i], fb[j], acc[i][j], 0, 0, 0);
    if (pf) STORET(cur ^ 1);
    __syncthreads();
    cur ^= 1;
  }
#undef LOADT
#undef STORET

  int r0 = kg * 4;
#pragma unroll
  for (int i = 0; i < 4; i++) {
    int gmBase = bm + wr * 64 + i * 16 + r0;
#pragma unroll
    for (int r = 0; r < 4; r++) {
      int gm = gmBase + r;
      if (gm >= M) continue;
#pragma unroll
      for (int j = 0; j < 4; j++) {
        int gn = bn + wc * 64 + j * 16 + l15;
        if (gn >= Nc) continue;
        float v = acc[i][j][r] + bias[gn];
        if (RELU) v = fmaxf(v, 0.f);
        if (OMODE == 0) {
          ((float*)Cout)[(size_t)gm * Nc + gn] = v;
        } else {  // fp16 sliced [Nc/32][M][32]
          size_t o = (size_t)(gn >> 5) * ((size_t)M * 32) + (size_t)gm * 32 + (gn & 31);
          ((unsigned short*)Cout)[o] = f2h(v);
        }
      }
    }
  }
}

// ---------------- classifier: BM=256, BN=48 (NOUT=40), sliced A, f32 out ----

__global__ __launch_bounds__(256) void k_cls(const unsigned short* __restrict__ Ag,
                                             const unsigned short* __restrict__ Btg,
                                             const float* __restrict__ bias,
                                             float* __restrict__ C, int M) {
  __shared__ unsigned short As[256 * 40];
  __shared__ unsigned short Bs[48 * 40];
  int tid = threadIdx.x;
  int lane = tid & 63, w = tid >> 6;
  int l15 = lane & 15, kg = lane >> 4;
  int bm = blockIdx.x * 256;

  f32x4 zero = {0.f, 0.f, 0.f, 0.f};
  f32x4 acc[4][3];
#pragma unroll
  for (int i = 0; i < 4; i++)
#pragma unroll
    for (int j = 0; j < 3; j++) acc[i][j] = zero;

  for (int kt = 0; kt < HID; kt += 32) {
    const unsigned short* Ab = Ag + (size_t)(kt >> 5) * ((size_t)M * 32);
#pragma unroll
    for (int it = 0; it < 4; it++) {
      int c = tid + it * 256;
      int row = c >> 2, kq = (c & 3) * 8;
      int gm = bm + row;
      uint4 v = {0, 0, 0, 0};
      if (gm < M) v = *reinterpret_cast<const uint4*>(Ab + (size_t)gm * 32 + kq);
      *reinterpret_cast<uint4*>(&As[row * 40 + kq]) = v;
    }
    if (tid < 192) {
      int row = tid >> 2, kq = (tid & 3) * 8;
      *reinterpret_cast<uint4*>(&Bs[row * 40 + kq]) =
          *reinterpret_cast<const uint4*>(Btg + (size_t)row * HID + kt + kq);
    }
    __syncthreads();
    f16x8 fa[4], fb[3];
#pragma unroll
    for (int f = 0; f < 4; f++)
      fa[f] = *reinterpret_cast<const f16x8*>(&As[(w * 64 + f * 16 + l15) * 40 + kg * 8]);
#pragma unroll
    for (int j = 0; j < 3; j++)
      fb[j] = *reinterpret_cast<const f16x8*>(&Bs[(j * 16 + l15) * 40 + kg * 8]);
#pragma unroll
    for (int i = 0; i < 4; i++)
#pragma unroll
      for (int j = 0; j < 3; j++)
        acc[i][j] = __builtin_amdgcn_mfma_f32_16x16x32_f16(fa[i], fb[j], acc[i][j], 0, 0, 0);
    __syncthreads();
  }

  int r0 = kg * 4;
#pragma unroll
  for (int i = 0; i < 4; i++) {
    int gmBase = bm + w * 64 + i * 16 + r0;
#pragma unroll
    for (int r = 0; r < 4; r++) {
      int gm = gmBase + r;
      if (gm >= M) continue;
#pragma unroll
      for (int j = 0; j < 3; j++) {
        int gn = j * 16 + l15;
        if (gn >= NOUT) continue;
        C[(size_t)gm * NOUT + gn] = acc[i][j][r] + bias[gn];
      }
    }
  }
}

// ---------------- launch ----------------

extern "C" void kernel_launch(void* const* d_in, const int* in_sizes, int n_in,
                              void* d_out, int out_size, void* d_ws, size_t ws_size,
                              hipStream_t stream) {
  (void)in_sizes; (void)n_in; (void)out_size; (void)ws_size;
  const float* x  = (const float*)d_in[0];
  const float* W1 = (const float*)d_in[1];
  const float* b1 = (const float*)d_in[2];
  const float* W2 = (const float*)d_in[3];
  const float* b2 = (const float*)d_in[4];
  const float* Wc = (const float*)d_in[5];
  const float* bc = (const float*)d_in[6];
  const int* edge = (const int*)d_in[7];
  const int* srcE = edge;
  const int* dstE = edge + NEDGES;
  float* out = (float*)d_out;

  char* ws = (char*)d_ws;
  int*   count    = (int*)(ws + 0);          // 200000 B
  int*   cursor   = (int*)(ws + 200064);
  int*   rowstart = (int*)(ws + 400128);     // per-block partial
  float* dinv     = (float*)(ws + 600320);
  int*   csr      = (int*)(ws + 800384);     // 3.2 MB
  int*   bsum     = (int*)(ws + 4000512);
  int*   boff     = (int*)(ws + 4001536);
  unsigned short* W1t = (unsigned short*)(ws + 4002560);   // 256x128 fp16
  unsigned short* W2t = (unsigned short*)(ws + 4068096);   // 256x256 fp16
  unsigned short* Wct = (unsigned short*)(ws + 4199168);   // 48x256 fp16
  unsigned short* xh  = (unsigned short*)(ws + 4264704);   // sliced 4x[N][32]
  unsigned short* aggx = (unsigned short*)(ws + 17064704); // sliced 4x[N][32]
  unsigned short* h1   = (unsigned short*)(ws + 29864704); // sliced 8x[N][32]
  unsigned short* aggh = (unsigned short*)(ws + 55464704); // sliced 8x[N][32]
  unsigned short* h2   = (unsigned short*)(ws + 81064704); // sliced 8x[N][32]

  hipMemsetAsync(ws, 0, 400128, stream);  // count + cursor

  k_pre<<<NBLK_CAST + NBLK_DEG + NBLK_PREP, 256, 0, stream>>>(
      x, xh, dstE, count, W1, W2, Wc, W1t, W2t, Wct);
  k_scan1<<<NBLK_SCAN, 256, 0, stream>>>(count, rowstart, bsum, dinv);
  k_scan2<<<1, 256, 0, stream>>>(bsum, boff);
  k_scatter<<<NBLK_DEG, 256, 0, stream>>>(srcE, dstE, rowstart, boff, cursor, csr);

  // layer 1: sliced agg (4 slabs) + GEMM (sliced A, sliced out)
  k_aggs<4><<<NCHUNK_AGG << 2, 256, 0, stream>>>(xh, rowstart, boff, csr, dinv, aggx);
  {
    dim3 grid((NNODES + 127) / 128, HID / 128);
    k_mgemm<1, 1, 1><<<grid, 256, 0, stream>>>(aggx, W1t, b1, (void*)h1, NNODES, HID, F_IN);
  }
  // layer 2: sliced agg (8 slabs, 1 XCD each)
  k_aggs<8><<<NCHUNK_AGG << 3, 256, 0, stream>>>(h1, rowstart, boff, csr, dinv, aggh);
  {
    dim3 grid((NNODES + 127) / 128, HID / 128);
    k_mgemm<1, 1, 1><<<grid, 256, 0, stream>>>(aggh, W2t, b2, (void*)h2, NNODES, HID, HID);
  }
  // classifier (sliced A)
  k_cls<<<(NNODES + 255) / 256, 256, 0, stream>>>(h2, Wct, bc, out, NNODES);
}

// Round 13
// 308.697 us; speedup vs baseline: 1.2053x; 1.2053x over previous
//
#include <hip/hip_runtime.h>

#define NNODES 50000
#define NEDGES 800000
#define F_IN   128
#define HID    256
#define NOUT   40
#define NBLK_SCAN ((NNODES + 255) / 256)  // 196
#define NBLK_CAST 6250                     // 50000*128/4/256
#define NBLK_DEG  2048                     // partitioned: 256 chunks x 8 groups
#define NBLK_PREP 432                      // 128 (W1) + 256 (W2) + 48 (Wc)
#define EDGE_CHUNK 3125                    // 800000 / 256
#define NODES_PER_G 6250                   // 50000 / 8

typedef __attribute__((ext_vector_type(8))) _Float16 f16x8;
typedef __attribute__((ext_vector_type(4))) float f32x4;
typedef __attribute__((ext_vector_type(4))) unsigned short u16x4;
typedef __attribute__((ext_vector_type(8))) unsigned short u16x8;

__device__ __forceinline__ unsigned short f2h(float f) {
  return __builtin_bit_cast(unsigned short, (_Float16)f);
}
__device__ __forceinline__ float h2f(unsigned short u) {
  return (float)__builtin_bit_cast(_Float16, u);
}

// ------- fused: x->fp16 cast | XCD-local degree | weight transpose ---------

__global__ __launch_bounds__(256) void k_pre(const float* __restrict__ X,
                                             unsigned short* __restrict__ Xh,
                                             const int* __restrict__ dst,
                                             int* __restrict__ count,
                                             const float* __restrict__ W1,
                                             const float* __restrict__ W2,
                                             const float* __restrict__ Wc,
                                             unsigned short* __restrict__ T1,
                                             unsigned short* __restrict__ T2,
                                             unsigned short* __restrict__ Tc) {
  int b = blockIdx.x, t = threadIdx.x;
  if (b < NBLK_CAST) {
    int i = b * 256 + t;
    float4 v = *reinterpret_cast<const float4*>(X + (size_t)i * 4);
    ushort4 o;
    o.x = f2h(v.x); o.y = f2h(v.y); o.z = f2h(v.z); o.w = f2h(v.w);
    *reinterpret_cast<ushort4*>(Xh + (size_t)i * 4) = o;
  } else if (b < NBLK_CAST + NBLK_DEG) {
    int db = b - NBLK_CAST;
    int g = b & 7;                 // hardware XCD (round-robin heuristic)
    int chunk = db >> 3;           // 0..255
    int lo = g * NODES_PER_G, hi = lo + NODES_PER_G;
    int base = chunk * EDGE_CHUNK;
    for (int i = base + t; i < base + EDGE_CHUNK; i += 256) {
      int d = dst[i];
      if (d >= lo && d < hi) atomicAdd(&count[d], 1);
    }
  } else {
    int pb = b - NBLK_CAST - NBLK_DEG;  // 0..431
    if (pb < 128) {                     // W1 [128][256] -> T1 [256][128]
      int idx = pb * 256 + t;
      int n = idx >> 7, k = idx & 127;
      T1[idx] = f2h(W1[(size_t)k * HID + n]);
    } else if (pb < 384) {              // W2 [256][256] -> T2 [256][256]
      int idx = (pb - 128) * 256 + t;
      int n = idx >> 8, k = idx & 255;
      T2[idx] = f2h(W2[(size_t)k * HID + n]);
    } else {                            // Wc [256][40] -> Tc [48][256] zero-pad
      int idx = (pb - 384) * 256 + t;
      int n = idx >> 8, k = idx & 255;
      float v = (n < NOUT) ? Wc[(size_t)k * NOUT + n] : 0.f;
      Tc[idx] = f2h(v);
    }
  }
}

// ---------------- CSR scan (scan2 fused via last-block pattern) ------------

__global__ __launch_bounds__(256) void k_scan1(const int* __restrict__ count,
                                               int* __restrict__ rowstart,
                                               int* __restrict__ bsum,
                                               float* __restrict__ dinv,
                                               int* __restrict__ boff,
                                               int* __restrict__ done) {
  __shared__ int tmp[256];
  __shared__ int lastFlag;
  int t = threadIdx.x;
  int i = blockIdx.x * 256 + t;
  int v = (i < NNODES) ? count[i] : 0;
  if (i < NNODES) dinv[i] = rsqrtf((float)(v + 1));  // +1 self-loop
  tmp[t] = v;
  __syncthreads();
  for (int off = 1; off < 256; off <<= 1) {
    int x = (t >= off) ? tmp[t - off] : 0;
    __syncthreads();
    tmp[t] += x;
    __syncthreads();
  }
  if (i < NNODES) rowstart[i] = tmp[t] - v;  // exclusive within block
  if (t == 255) {
    bsum[blockIdx.x] = tmp[255];
    __threadfence();  // release: bsum visible before done increment
  }
  __syncthreads();
  if (t == 0) lastFlag = (atomicAdd(done, 1) == (int)gridDim.x - 1);
  __syncthreads();
  if (lastFlag) {  // last-finishing block performs the 196-element prefix
    __threadfence();  // acquire: see all other blocks' bsum
    int v2 = (t < NBLK_SCAN) ? bsum[t] : 0;
    tmp[t] = v2;
    __syncthreads();
    for (int off = 1; off < 256; off <<= 1) {
      int x2 = (t >= off) ? tmp[t - off] : 0;
      __syncthreads();
      tmp[t] += x2;
      __syncthreads();
    }
    if (t < NBLK_SCAN) boff[t] = tmp[t] - v2;  // exclusive
  }
}

// ---------------- XCD-local scatter ----------------

__global__ __launch_bounds__(256) void k_scatter(const int* __restrict__ src,
                                                 const int* __restrict__ dst,
                                                 const int* __restrict__ rowstart,
                                                 const int* __restrict__ boff,
                                                 int* __restrict__ cursor,
                                                 int* __restrict__ csr) {
  int g = blockIdx.x & 7;
  int chunk = blockIdx.x >> 3;
  int lo = g * NODES_PER_G, hi = lo + NODES_PER_G;
  int base = chunk * EDGE_CHUNK;
  for (int i = base + threadIdx.x; i < base + EDGE_CHUNK; i += 256) {
    int d = dst[i];
    if (d >= lo && d < hi) {
      int p = rowstart[d] + boff[d >> 8] + atomicAdd(&cursor[d], 1);
      csr[p] = src[i];
    }
  }
}

// ---------------- agg layer 1: half-wave fp16 gather (F=128) ----------------

__global__ __launch_bounds__(256) void k_agg1(const unsigned short* __restrict__ X,
                                              const int* __restrict__ rowstart,
                                              const int* __restrict__ boff,
                                              const int* __restrict__ csr,
                                              const float* __restrict__ dinv,
                                              uint2* __restrict__ Y) {
  int wave = threadIdx.x >> 6, lane = threadIdx.x & 63;
  int node = blockIdx.x * 4 + wave;
  if (node >= NNODES) return;
  int half = lane >> 5, l32 = lane & 31;
  float di = dinv[node];
  float a[4] = {0.f, 0.f, 0.f, 0.f};
  int e = rowstart[node] + boff[node >> 8];
  int end = (node + 1 < NNODES) ? rowstart[node + 1] + boff[(node + 1) >> 8] : NEDGES;
  for (; e + 8 <= end; e += 8) {
    int s0 = csr[e + 0 + half], s1 = csr[e + 2 + half];
    int s2 = csr[e + 4 + half], s3 = csr[e + 6 + half];
    float w0 = dinv[s0] * di, w1 = dinv[s1] * di;
    float w2 = dinv[s2] * di, w3 = dinv[s3] * di;
    u16x4 r0 = *reinterpret_cast<const u16x4*>(X + (size_t)s0 * F_IN + l32 * 4);
    u16x4 r1 = *reinterpret_cast<const u16x4*>(X + (size_t)s1 * F_IN + l32 * 4);
    u16x4 r2 = *reinterpret_cast<const u16x4*>(X + (size_t)s2 * F_IN + l32 * 4);
    u16x4 r3 = *reinterpret_cast<const u16x4*>(X + (size_t)s3 * F_IN + l32 * 4);
#pragma unroll
    for (int k = 0; k < 4; k++) {
      a[k] = fmaf(h2f(r0[k]), w0, a[k]);
      a[k] = fmaf(h2f(r1[k]), w1, a[k]);
      a[k] = fmaf(h2f(r2[k]), w2, a[k]);
      a[k] = fmaf(h2f(r3[k]), w3, a[k]);
    }
  }
  for (; e + 2 <= end; e += 2) {
    int s = csr[e + half];
    float w = dinv[s] * di;
    u16x4 r = *reinterpret_cast<const u16x4*>(X + (size_t)s * F_IN + l32 * 4);
#pragma unroll
    for (int k = 0; k < 4; k++) a[k] = fmaf(h2f(r[k]), w, a[k]);
  }
  if (e < end) {  // odd remainder: both halves read it, half 1 weight 0
    int s = csr[e];
    float w = half ? 0.f : dinv[s] * di;
    u16x4 r = *reinterpret_cast<const u16x4*>(X + (size_t)s * F_IN + l32 * 4);
#pragma unroll
    for (int k = 0; k < 4; k++) a[k] = fmaf(h2f(r[k]), w, a[k]);
  }
#pragma unroll
  for (int k = 0; k < 4; k++) a[k] += __shfl_xor(a[k], 32);
  if (half == 0) {
    u16x4 self = *reinterpret_cast<const u16x4*>(X + (size_t)node * F_IN + l32 * 4);
    float dd = di * di;
#pragma unroll
    for (int k = 0; k < 4; k++) a[k] = fmaf(h2f(self[k]), dd, a[k]);
    uint2 o;
    o.x = (unsigned)f2h(a[0]) | ((unsigned)f2h(a[1]) << 16);
    o.y = (unsigned)f2h(a[2]) | ((unsigned)f2h(a[3]) << 16);
    Y[(size_t)node * 32 + l32] = o;
  }
}

// ---------------- agg layer 2: half-wave fp16 gather (F=256) ----------------

__global__ __launch_bounds__(256) void k_agg2(const unsigned short* __restrict__ H,
                                              const int* __restrict__ rowstart,
                                              const int* __restrict__ boff,
                                              const int* __restrict__ csr,
                                              const float* __restrict__ dinv,
                                              uint4* __restrict__ Y) {
  int wave = threadIdx.x >> 6, lane = threadIdx.x & 63;
  int node = blockIdx.x * 4 + wave;
  if (node >= NNODES) return;
  int half = lane >> 5, l32 = lane & 31;
  float di = dinv[node];
  float a[8] = {0.f, 0.f, 0.f, 0.f, 0.f, 0.f, 0.f, 0.f};
  int e = rowstart[node] + boff[node >> 8];
  int end = (node + 1 < NNODES) ? rowstart[node + 1] + boff[(node + 1) >> 8] : NEDGES;
  for (; e + 8 <= end; e += 8) {
    int s0 = csr[e + 0 + half], s1 = csr[e + 2 + half];
    int s2 = csr[e + 4 + half], s3 = csr[e + 6 + half];
    float w0 = dinv[s0] * di, w1 = dinv[s1] * di;
    float w2 = dinv[s2] * di, w3 = dinv[s3] * di;
    u16x8 r0 = *reinterpret_cast<const u16x8*>(H + (size_t)s0 * HID + l32 * 8);
    u16x8 r1 = *reinterpret_cast<const u16x8*>(H + (size_t)s1 * HID + l32 * 8);
    u16x8 r2 = *reinterpret_cast<const u16x8*>(H + (size_t)s2 * HID + l32 * 8);
    u16x8 r3 = *reinterpret_cast<const u16x8*>(H + (size_t)s3 * HID + l32 * 8);
#pragma unroll
    for (int k = 0; k < 8; k++) {
      a[k] = fmaf(h2f(r0[k]), w0, a[k]);
      a[k] = fmaf(h2f(r1[k]), w1, a[k]);
      a[k] = fmaf(h2f(r2[k]), w2, a[k]);
      a[k] = fmaf(h2f(r3[k]), w3, a[k]);
    }
  }
  for (; e + 2 <= end; e += 2) {
    int s = csr[e + half];
    float w = dinv[s] * di;
    u16x8 r = *reinterpret_cast<const u16x8*>(H + (size_t)s * HID + l32 * 8);
#pragma unroll
    for (int k = 0; k < 8; k++) a[k] = fmaf(h2f(r[k]), w, a[k]);
  }
  if (e < end) {
    int s = csr[e];
    float w = half ? 0.f : dinv[s] * di;
    u16x8 r = *reinterpret_cast<const u16x8*>(H + (size_t)s * HID + l32 * 8);
#pragma unroll
    for (int k = 0; k < 8; k++) a[k] = fmaf(h2f(r[k]), w, a[k]);
  }
#pragma unroll
  for (int k = 0; k < 8; k++) a[k] += __shfl_xor(a[k], 32);
  if (half == 0) {
    u16x8 self = *reinterpret_cast<const u16x8*>(H + (size_t)node * HID + l32 * 8);
    float dd = di * di;
#pragma unroll
    for (int k = 0; k < 8; k++) a[k] = fmaf(h2f(self[k]), dd, a[k]);
    uint4 o;
    o.x = (unsigned)f2h(a[0]) | ((unsigned)f2h(a[1]) << 16);
    o.y = (unsigned)f2h(a[2]) | ((unsigned)f2h(a[3]) << 16);
    o.z = (unsigned)f2h(a[4]) | ((unsigned)f2h(a[5]) << 16);
    o.w = (unsigned)f2h(a[6]) | ((unsigned)f2h(a[7]) << 16);
    Y[(size_t)node * 32 + l32] = o;
  }
}

// ---------------- fp16 MFMA GEMM (layer 1), double-buffered ----------------
// C = A[MxK] @ B[KxN] + bias, ReLU, fp16 row-major out.

__global__ __launch_bounds__(256) void k_mgemm(const unsigned short* __restrict__ Ag,
                                               const unsigned short* __restrict__ Btg,
                                               const float* __restrict__ bias,
                                               unsigned short* __restrict__ Cout,
                                               int M, int Nc, int K) {
  __shared__ unsigned short Ah[2][128 * 40];
  __shared__ unsigned short Bh[2][128 * 40];
  int tid = threadIdx.x;
  int lane = tid & 63, w = tid >> 6;
  int wr = w >> 1, wc = w & 1;
  int bm = blockIdx.x * 128, bn = blockIdx.y * 128;
  int l15 = lane & 15, kg = lane >> 4;
  int row0 = tid >> 2, kq0 = (tid & 3) * 8;
  int gm0 = bm + row0, gm1 = bm + row0 + 64;

  f32x4 zero = {0.f, 0.f, 0.f, 0.f};
  f32x4 acc[4][4];
#pragma unroll
  for (int i = 0; i < 4; i++)
#pragma unroll
    for (int j = 0; j < 4; j++) acc[i][j] = zero;

  uint4 ra0, ra1, rb0, rb1;
  const uint4 z4 = {0, 0, 0, 0};
#define LOADT(KT)                                                                    \
  {                                                                                  \
    ra0 = z4; ra1 = z4;                                                              \
    if (gm0 < M) ra0 = *reinterpret_cast<const uint4*>(Ag + (size_t)gm0 * K + (KT) + kq0); \
    if (gm1 < M) ra1 = *reinterpret_cast<const uint4*>(Ag + (size_t)gm1 * K + (KT) + kq0); \
    rb0 = *reinterpret_cast<const uint4*>(Btg + (size_t)(bn + row0) * K + (KT) + kq0);     \
    rb1 = *reinterpret_cast<const uint4*>(Btg + (size_t)(bn + row0 + 64) * K + (KT) + kq0);\
  }
#define STORET(B)                                                       \
  {                                                                     \
    *reinterpret_cast<uint4*>(&Ah[B][row0 * 40 + kq0]) = ra0;           \
    *reinterpret_cast<uint4*>(&Ah[B][(row0 + 64) * 40 + kq0]) = ra1;    \
    *reinterpret_cast<uint4*>(&Bh[B][row0 * 40 + kq0]) = rb0;           \
    *reinterpret_cast<uint4*>(&Bh[B][(row0 + 64) * 40 + kq0]) = rb1;    \
  }

  LOADT(0);
  STORET(0);
  __syncthreads();
  int nt = K >> 5, cur = 0;
  for (int t = 0; t < nt; t++) {
    bool pf = (t + 1 < nt);
    if (pf) LOADT((t + 1) << 5);
    f16x8 fa[4], fb[4];
#pragma unroll
    for (int f = 0; f < 4; f++) {
      fa[f] = *reinterpret_cast<const f16x8*>(&Ah[cur][(wr * 64 + f * 16 + l15) * 40 + kg * 8]);
      fb[f] = *reinterpret_cast<const f16x8*>(&Bh[cur][(wc * 64 + f * 16 + l15) * 40 + kg * 8]);
    }
#pragma unroll
    for (int i = 0; i < 4; i++)
#pragma unroll
      for (int j = 0; j < 4; j++)
        acc[i][j] = __builtin_amdgcn_mfma_f32_16x16x32_f16(fa[i], fb[j], acc[i][j], 0, 0, 0);
    if (pf) STORET(cur ^ 1);
    __syncthreads();
    cur ^= 1;
  }
#undef LOADT
#undef STORET

  int r0 = kg * 4;
#pragma unroll
  for (int i = 0; i < 4; i++) {
    int gmBase = bm + wr * 64 + i * 16 + r0;
#pragma unroll
    for (int r = 0; r < 4; r++) {
      int gm = gmBase + r;
      if (gm >= M) continue;
#pragma unroll
      for (int j = 0; j < 4; j++) {
        int gn = bn + wc * 64 + j * 16 + l15;
        float v = acc[i][j][r] + bias[gn];
        v = fmaxf(v, 0.f);
        Cout[(size_t)gm * Nc + gn] = f2h(v);
      }
    }
  }
}

// ------- fused layer-2 GEMM + classifier: out = relu(aggh@W2+b2)@Wc + bc ----
// Per block: 128 rows. For each 128-col half of h2: compute h2half into LDS
// (single-buffered 128x32 staging), then MFMA against Wc k-slices,
// accumulating out[128][48]. h2 never touches global memory.

__global__ __launch_bounds__(256) void k_g2cls(const unsigned short* __restrict__ Ag,
                                               const unsigned short* __restrict__ W2t,
                                               const float* __restrict__ b2,
                                               const unsigned short* __restrict__ Wct,
                                               const float* __restrict__ bc,
                                               float* __restrict__ out, int M) {
  __shared__ unsigned short Ah[128 * 40];   // 10.2 KB
  __shared__ unsigned short Bh[128 * 40];   // 10.2 KB
  __shared__ unsigned short H2[128 * 136];  // 34.8 KB (pad 136 for reads)
  __shared__ unsigned short WcS[48 * 40];   // 3.8 KB
  int tid = threadIdx.x;
  int lane = tid & 63, w = tid >> 6;
  int wr = w >> 1, wc = w & 1;
  int bm = blockIdx.x * 128;
  int l15 = lane & 15, kg = lane >> 4;
  int row0 = tid >> 2, kq0 = (tid & 3) * 8;
  int gm0 = bm + row0, gm1 = bm + row0 + 64;

  f32x4 zero = {0.f, 0.f, 0.f, 0.f};
  f32x4 clsacc[2][3];
#pragma unroll
  for (int f = 0; f < 2; f++)
#pragma unroll
    for (int j = 0; j < 3; j++) clsacc[f][j] = zero;

  for (int halfN = 0; halfN < 2; halfN++) {
    // ---- phase 1: h2half[128][128] = relu(aggh_tile @ W2[:, half]) + b2 ----
    f32x4 acc[4][4];
#pragma unroll
    for (int i = 0; i < 4; i++)
#pragma unroll
      for (int j = 0; j < 4; j++) acc[i][j] = zero;
    int bn = halfN * 128;
    for (int kt = 0; kt < HID; kt += 32) {
      uint4 ra0 = {0, 0, 0, 0}, ra1 = {0, 0, 0, 0};
      if (gm0 < M) ra0 = *reinterpret_cast<const uint4*>(Ag + (size_t)gm0 * HID + kt + kq0);
      if (gm1 < M) ra1 = *reinterpret_cast<const uint4*>(Ag + (size_t)gm1 * HID + kt + kq0);
      uint4 rb0 = *reinterpret_cast<const uint4*>(W2t + (size_t)(bn + row0) * HID + kt + kq0);
      uint4 rb1 = *reinterpret_cast<const uint4*>(W2t + (size_t)(bn + row0 + 64) * HID + kt + kq0);
      *reinterpret_cast<uint4*>(&Ah[row0 * 40 + kq0]) = ra0;
      *reinterpret_cast<uint4*>(&Ah[(row0 + 64) * 40 + kq0]) = ra1;
      *reinterpret_cast<uint4*>(&Bh[row0 * 40 + kq0]) = rb0;
      *reinterpret_cast<uint4*>(&Bh[(row0 + 64) * 40 + kq0]) = rb1;
      __syncthreads();
      f16x8 fa[4], fb[4];
#pragma unroll
      for (int f = 0; f < 4; f++) {
        fa[f] = *reinterpret_cast<const f16x8*>(&Ah[(wr * 64 + f * 16 + l15) * 40 + kg * 8]);
        fb[f] = *reinterpret_cast<const f16x8*>(&Bh[(wc * 64 + f * 16 + l15) * 40 + kg * 8]);
      }
#pragma unroll
      for (int i = 0; i < 4; i++)
#pragma unroll
        for (int j = 0; j < 4; j++)
          acc[i][j] = __builtin_amdgcn_mfma_f32_16x16x32_f16(fa[i], fb[j], acc[i][j], 0, 0, 0);
      __syncthreads();
    }
    // epilogue into H2 LDS (bias + relu, fp16)
    int r0 = kg * 4;
#pragma unroll
    for (int i = 0; i < 4; i++)
#pragma unroll
      for (int r = 0; r < 4; r++) {
        int lrow = wr * 64 + i * 16 + r0 + r;
#pragma unroll
        for (int j = 0; j < 4; j++) {
          int lcol = wc * 64 + j * 16 + l15;
          float v = acc[i][j][r] + b2[bn + lcol];
          H2[lrow * 136 + lcol] = f2h(fmaxf(v, 0.f));
        }
      }
    __syncthreads();
    // ---- phase 2: clsacc += h2half @ Wc[half*128:(half+1)*128, :48] ----
    for (int kt2 = 0; kt2 < 128; kt2 += 32) {
      if (tid < 192) {  // stage Wc^T slice: 48 rows x 32 k
        int row = tid >> 2, kq = (tid & 3) * 8;
        *reinterpret_cast<uint4*>(&WcS[row * 40 + kq]) =
            *reinterpret_cast<const uint4*>(Wct + (size_t)row * HID + halfN * 128 + kt2 + kq);
      }
      __syncthreads();
      f16x8 fa[2], fb[3];
#pragma unroll
      for (int f = 0; f < 2; f++)
        fa[f] = *reinterpret_cast<const f16x8*>(&H2[(w * 32 + f * 16 + l15) * 136 + kt2 + kg * 8]);
#pragma unroll
      for (int j = 0; j < 3; j++)
        fb[j] = *reinterpret_cast<const f16x8*>(&WcS[(j * 16 + l15) * 40 + kg * 8]);
#pragma unroll
      for (int f = 0; f < 2; f++)
#pragma unroll
        for (int j = 0; j < 3; j++)
          clsacc[f][j] = __builtin_amdgcn_mfma_f32_16x16x32_f16(fa[f], fb[j], clsacc[f][j], 0, 0, 0);
      __syncthreads();
    }
  }
  // ---- final store: out[128][40] fp32 ----
  int r0 = kg * 4;
#pragma unroll
  for (int f = 0; f < 2; f++) {
    int gmBase = bm + w * 32 + f * 16 + r0;
#pragma unroll
    for (int r = 0; r < 4; r++) {
      int gm = gmBase + r;
      if (gm >= M) continue;
#pragma unroll
      for (int j = 0; j < 3; j++) {
        int gn = j * 16 + l15;
        if (gn >= NOUT) continue;
        out[(size_t)gm * NOUT + gn] = clsacc[f][j][r] + bc[gn];
      }
    }
  }
}

// ---------------- launch ----------------

extern "C" void kernel_launch(void* const* d_in, const int* in_sizes, int n_in,
                              void* d_out, int out_size, void* d_ws, size_t ws_size,
                              hipStream_t stream) {
  (void)in_sizes; (void)n_in; (void)out_size; (void)ws_size;
  const float* x  = (const float*)d_in[0];
  const float* W1 = (const float*)d_in[1];
  const float* b1 = (const float*)d_in[2];
  const float* W2 = (const float*)d_in[3];
  const float* b2 = (const float*)d_in[4];
  const float* Wc = (const float*)d_in[5];
  const float* bc = (const float*)d_in[6];
  const int* edge = (const int*)d_in[7];
  const int* srcE = edge;
  const int* dstE = edge + NEDGES;
  float* out = (float*)d_out;

  char* ws = (char*)d_ws;
  int*   count    = (int*)(ws + 0);          // 200000 B
  int*   cursor   = (int*)(ws + 200064);     // 200000 B (ends 400064)
  int*   done     = (int*)(ws + 400064);     // 4 B (inside memset range)
  int*   rowstart = (int*)(ws + 400128);     // per-block partial
  float* dinv     = (float*)(ws + 600320);
  int*   csr      = (int*)(ws + 800384);     // 3.2 MB
  int*   bsum     = (int*)(ws + 4000512);
  int*   boff     = (int*)(ws + 4001536);
  unsigned short* W1t = (unsigned short*)(ws + 4002560);   // 256x128 fp16
  unsigned short* W2t = (unsigned short*)(ws + 4068096);   // 256x256 fp16
  unsigned short* Wct = (unsigned short*)(ws + 4199168);   // 48x256 fp16
  unsigned short* xh  = (unsigned short*)(ws + 4264704);   // 50000x128 fp16
  unsigned short* aggx = (unsigned short*)(ws + 17064704); // 50000x128 fp16
  unsigned short* h1   = (unsigned short*)(ws + 29864704); // 50000x256 fp16
  unsigned short* aggh = (unsigned short*)(ws + 55464704); // 50000x256 fp16

  hipMemsetAsync(ws, 0, 400128, stream);  // count + cursor + done

  k_pre<<<NBLK_CAST + NBLK_DEG + NBLK_PREP, 256, 0, stream>>>(
      x, xh, dstE, count, W1, W2, Wc, W1t, W2t, Wct);
  k_scan1<<<NBLK_SCAN, 256, 0, stream>>>(count, rowstart, bsum, dinv, boff, done);
  k_scatter<<<NBLK_DEG, 256, 0, stream>>>(srcE, dstE, rowstart, boff, cursor, csr);

  // layer 1
  k_agg1<<<(NNODES + 3) / 4, 256, 0, stream>>>(xh, rowstart, boff, csr, dinv, (uint2*)aggx);
  {
    dim3 grid((NNODES + 127) / 128, HID / 128);
    k_mgemm<<<grid, 256, 0, stream>>>(aggx, W1t, b1, h1, NNODES, HID, F_IN);
  }
  // layer 2 + classifier (fused)
  k_agg2<<<(NNODES + 3) / 4, 256, 0, stream>>>(h1, rowstart, boff, csr, dinv, (uint4*)aggh);
  k_g2cls<<<(NNODES + 127) / 128, 256, 0, stream>>>(aggh, W2t, b2, Wct, bc, out, NNODES);
}